// Round 13
// baseline (286.663 us; speedup 1.0000x reference)
//
#include <hip/hip_runtime.h>
#include <hip/hip_bf16.h>
#include <math.h>

#define NFEATS 128
#define NHID   64
#define NCLS   40
#define NEG_SLOPE 0.01f

#define GSH_S  9                // log2(stage group span)
#define GSPAN_S 512             // nodes per stage group
#define GCAP_S 9216             // staged capacity per group (mean 8192, +11 sigma)
#define SB     2048             // edges per stage block (4/thread at 512 threads)

typedef float f32x4 __attribute__((ext_vector_type(4)));
typedef int   i32x2 __attribute__((ext_vector_type(2)));

// bf16 helpers (raw ushort storage, RNE rounding)
__device__ inline unsigned short f2bfu(float v) {
    union { float f; unsigned int u; } x; x.f = v;
    unsigned int r = (x.u + 0x7FFFu + ((x.u >> 16) & 1u)) >> 16;
    return (unsigned short)r;
}
__device__ inline float bf2f(unsigned short u) {
    union { unsigned int u32; float f; } x; x.u32 = ((unsigned int)u) << 16;
    return x.f;
}

// ---- role split: interleave nA blocks with nB blocks (1:1 striping, then tail) ----
__device__ inline void role_split(int i, int nA, int nB, int* ia, int* ib) {
    *ia = -1; *ib = -1;
    int m2 = 2 * min(nA, nB);
    if (i < m2) { if (i & 1) *ib = i >> 1; else *ia = i >> 1; }
    else if (nA > nB) *ia = i - nB;
    else *ib = i - nA;
}

// ---------------- K2: staged binning (512 thr, 4 edges/thr) + GEMM1 (128x64 tile) ----------------

__global__ __launch_bounds__(512) void stage_gemm1_kernel(
    const int* __restrict__ srcA, const int* __restrict__ dstA, const float* __restrict__ ew,
    int* __restrict__ gcur, int2* __restrict__ staged, int E, int nStage, int ngrp,
    const float* __restrict__ x, const float* __restrict__ W1, const float* __restrict__ b1,
    float* __restrict__ h1, int n, int nTile) {
    __shared__ __align__(16) float Ws[64 * 64];   // 16KB; stage role aliases as int[512]

    int ia, ib;
    role_split(blockIdx.x, nStage, nTile, &ia, &ib);
    int tid = threadIdx.x;

    if (ia >= 0) {
        int* hist = (int*)Ws;         // [256] (ngrp<=256)
        int* wcur = ((int*)Ws) + 256; // [256]
        if (tid < 256) hist[tid] = 0;
        __syncthreads();

        int q0 = (ia * SB) >> 2;                 // int4-quad base (512 quads/block)
        int qend = min(q0 + SB / 4, E >> 2);
        int q = q0 + tid;
        int dcache[4];

        // pass A: dst -> regs + histogram
        {
            int4 d4 = (q < qend) ? ((const int4*)dstA)[q] : make_int4(-1, -1, -1, -1);
            dcache[0] = d4.x; dcache[1] = d4.y; dcache[2] = d4.z; dcache[3] = d4.w;
#pragma unroll
            for (int j = 0; j < 4; ++j)
                if (dcache[j] >= 0) atomicAdd(&hist[dcache[j] >> GSH_S], 1);
        }
        if (ia == nStage - 1) {
            for (int e = (E & ~3) + tid; e < E; e += 512) atomicAdd(&hist[dstA[e] >> GSH_S], 1);
        }
        __syncthreads();

        // reserve per-group regions
        if (tid < ngrp) {
            int c = hist[tid];
            wcur[tid] = (c > 0) ? atomicAdd(&gcur[tid], c) : 0;
        }
        __syncthreads();

        // pass B: src/ew loads + scatter records (4 independent atomic->store pairs)
        if (q < qend) {
            int4 s4 = ((const int4*)srcA)[q];
            float4 w4 = ((const float4*)ew)[q];
            int ss[4] = {s4.x, s4.y, s4.z, s4.w};
            float ww[4] = {w4.x, w4.y, w4.z, w4.w};
#pragma unroll
            for (int j = 0; j < 4; ++j) {
                int d = dcache[j];
                int g = d >> GSH_S;
                int pos = atomicAdd(&wcur[g], 1);
                if (pos < GCAP_S)
                    staged[(size_t)g * GCAP_S + pos] =
                        make_int2(((d & (GSPAN_S - 1)) << 17) | ss[j], __float_as_int(ww[j]));
            }
        }
        if (ia == nStage - 1) {
            for (int e = (E & ~3) + tid; e < E; e += 512) {
                int d = dstA[e];
                int g = d >> GSH_S;
                int pos = atomicAdd(&wcur[g], 1);
                if (pos < GCAP_S)
                    staged[(size_t)g * GCAP_S + pos] =
                        make_int2(((d & (GSPAN_S - 1)) << 17) | srcA[e], __float_as_int(ew[e]));
            }
        }
        return;
    }

    // ---- gemm role: h1 = lrelu(x @ W1 + b1), 128x64 tile, 4x4 micro-tile, 512 thr ----
    int c4 = (tid & 15) * 4;
    int r0 = ib * 128 + (tid >> 4) * 4;
    int rr[4];
#pragma unroll
    for (int i = 0; i < 4; ++i) rr[i] = min(r0 + i, n - 1);

    float acc[4][4] = {};
    for (int ph = 0; ph < 2; ++ph) {
        __syncthreads();
        for (int i = tid; i < 64 * 16; i += 512)
            ((float4*)Ws)[i] = ((const float4*)W1)[ph * 1024 + i];
        __syncthreads();
#pragma unroll 2
        for (int kk = 0; kk < 64; kk += 4) {
            f32x4 av[4], bv[4];
#pragma unroll
            for (int i = 0; i < 4; ++i)
                av[i] = __builtin_nontemporal_load(
                    (const f32x4*)&x[(size_t)rr[i] * NFEATS + ph * 64 + kk]);
#pragma unroll
            for (int qq = 0; qq < 4; ++qq) bv[qq] = *(const f32x4*)&Ws[(kk + qq) * 64 + c4];
#pragma unroll
            for (int i = 0; i < 4; ++i) {
#pragma unroll
                for (int qq = 0; qq < 4; ++qq) {
                    float a = av[i][qq];
#pragma unroll
                    for (int j = 0; j < 4; ++j) acc[i][j] += a * bv[qq][j];
                }
            }
        }
    }

#pragma unroll
    for (int i = 0; i < 4; ++i) {
        int rw = r0 + i;
        if (rw >= n) break;
        float4 o;
        float* oa = (float*)&o;
#pragma unroll
        for (int j = 0; j < 4; ++j) {
            float v = acc[i][j] + b1[c4 + j];
            oa[j] = (v > 0.0f) ? v : v * NEG_SLOPE;
        }
        *(float4*)&h1[(size_t)rw * 64 + c4] = o;
    }
}

// ---------------- K3: merged deg/dis + node-sort (1024 thr, one block per coarse group) ----------------

__global__ __launch_bounds__(1024) void degsort_kernel(
    const int* __restrict__ gcur, const int2* __restrict__ staged,
    int2* __restrict__ staged2, float* __restrict__ dis,
    int2* __restrict__ nodeptr, int n) {
    __shared__ float deg[GSPAN_S];
    __shared__ int hist[GSPAN_S], base[GSPAN_S], cur[GSPAN_S];

    int tid = threadIdx.x;
    int g = blockIdx.x;
    if (tid < GSPAN_S) { deg[tid] = 0.0f; hist[tid] = 0; }
    __syncthreads();

    int cnt = min(gcur[g], GCAP_S);
    const int2* sl = staged + (size_t)g * GCAP_S;
    for (int i = tid; i < cnt; i += 1024) {
        int2 r = sl[i];
        int dl = r.x >> 17;
        atomicAdd(&deg[dl], __int_as_float(r.y));
        atomicAdd(&hist[dl], 1);
    }
    __syncthreads();

    int node = g * GSPAN_S + tid;
    if (tid < GSPAN_S && node < n) dis[node] = rsqrtf(1.0f + deg[tid]);

    // exclusive scan of hist (512 entries)
    if (tid < GSPAN_S) base[tid] = hist[tid];
    __syncthreads();
    for (int off = 1; off < GSPAN_S; off <<= 1) {
        int t_ = 0;
        if (tid < GSPAN_S && tid >= off) t_ = base[tid - off];
        __syncthreads();
        if (tid < GSPAN_S) base[tid] += t_;
        __syncthreads();
    }
    if (tid < GSPAN_S) {
        int ex = base[tid] - hist[tid];
        base[tid] = ex;
        cur[tid] = ex;
        if (node < n) nodeptr[node] = make_int2(g * GCAP_S + ex, hist[tid]);
    }
    __syncthreads();

    int2* out = staged2 + (size_t)g * GCAP_S;
    for (int i = tid; i < cnt; i += 1024) {
        int2 r = sl[i];
        int dl = r.x >> 17;
        int pos = atomicAdd(&cur[dl], 1);
        out[pos] = make_int2(r.x & 0x1FFFF, r.y);
    }
}

// ---------------- K4: GEMM2 standalone: t1' = dis ⊙ (h1 @ Wc1) -> bf16 ----------------

__global__ __launch_bounds__(256) void gemm2s_kernel(
    const float* __restrict__ in, const float* __restrict__ W, const float* __restrict__ dis,
    unsigned short* __restrict__ outp, int n) {
    __shared__ __align__(16) float Ws[NHID * 64];
    int tid = threadIdx.x;
    for (int i = tid; i < NHID * 16; i += 256) ((float4*)Ws)[i] = ((const float4*)W)[i];
    __syncthreads();

    int c4 = (tid & 15) * 4;
    int r0 = blockIdx.x * 64 + (tid >> 4) * 4;
    int rr[4];
#pragma unroll
    for (int i = 0; i < 4; ++i) rr[i] = min(r0 + i, n - 1);

    float acc[4][4] = {};
#pragma unroll 2
    for (int kk = 0; kk < NHID; kk += 4) {
        f32x4 av[4], bv[4];
#pragma unroll
        for (int i = 0; i < 4; ++i)
            av[i] = __builtin_nontemporal_load((const f32x4*)&in[(size_t)rr[i] * NHID + kk]);
#pragma unroll
        for (int q = 0; q < 4; ++q) bv[q] = *(const f32x4*)&Ws[(kk + q) * 64 + c4];
#pragma unroll
        for (int i = 0; i < 4; ++i) {
#pragma unroll
            for (int q = 0; q < 4; ++q) {
                float a = av[i][q];
#pragma unroll
                for (int j = 0; j < 4; ++j) acc[i][j] += a * bv[q][j];
            }
        }
    }

#pragma unroll
    for (int i = 0; i < 4; ++i) {
        int rw = r0 + i;
        if (rw >= n) break;
        float dr = dis[rw];
        ushort4 o;
        o.x = f2bfu(dr * acc[i][0]); o.y = f2bfu(dr * acc[i][1]);
        o.z = f2bfu(dr * acc[i][2]); o.w = f2bfu(dr * acc[i][3]);
        *(ushort4*)&outp[(size_t)rw * 64 + c4] = o;
    }
}

// ---------------- K5/K6: aggregation (wave per node, bf16 row gathers, 8 chains) ----------------

template <int LAYER>
__global__ __launch_bounds__(256) void agg_kernel(const int2* __restrict__ nodeptr,
                                                  const int2* __restrict__ recs0,
                                                  const unsigned short* __restrict__ tb,
                                                  const float* __restrict__ dis,
                                                  const float* __restrict__ bias,
                                                  unsigned short* __restrict__ outp, int n) {
    int wv = threadIdx.x >> 6;
    int lane = threadIdx.x & 63;
    int node = blockIdx.x * 4 + wv;
    if (node >= n) return;

    int2 np = nodeptr[node];
    int start = np.x, c = np.y;
    float a0 = bf2f(tb[(size_t)node * NHID + lane]);   // self term t'[d]
    float a1 = 0.0f, a2 = 0.0f, a3 = 0.0f;
    float a4 = 0.0f, a5 = 0.0f, a6 = 0.0f, a7 = 0.0f;

    const i32x2* recs = (const i32x2*)(recs0 + start);
    for (int b = 0; b < c; b += 64) {
        int rem = min(64, c - b);
        i32x2 ent = (lane < rem) ? __builtin_nontemporal_load(recs + b + lane) : (i32x2){0, 0};
        int k = 0;
        for (; k + 7 < rem; k += 8) {
            int s0 = __shfl(ent[0], k);     float w0 = __int_as_float(__shfl(ent[1], k));
            int s1 = __shfl(ent[0], k + 1); float w1 = __int_as_float(__shfl(ent[1], k + 1));
            int s2 = __shfl(ent[0], k + 2); float w2 = __int_as_float(__shfl(ent[1], k + 2));
            int s3 = __shfl(ent[0], k + 3); float w3 = __int_as_float(__shfl(ent[1], k + 3));
            int s4 = __shfl(ent[0], k + 4); float w4 = __int_as_float(__shfl(ent[1], k + 4));
            int s5 = __shfl(ent[0], k + 5); float w5 = __int_as_float(__shfl(ent[1], k + 5));
            int s6 = __shfl(ent[0], k + 6); float w6 = __int_as_float(__shfl(ent[1], k + 6));
            int s7 = __shfl(ent[0], k + 7); float w7 = __int_as_float(__shfl(ent[1], k + 7));
            a0 += w0 * bf2f(tb[(size_t)s0 * NHID + lane]);
            a1 += w1 * bf2f(tb[(size_t)s1 * NHID + lane]);
            a2 += w2 * bf2f(tb[(size_t)s2 * NHID + lane]);
            a3 += w3 * bf2f(tb[(size_t)s3 * NHID + lane]);
            a4 += w4 * bf2f(tb[(size_t)s4 * NHID + lane]);
            a5 += w5 * bf2f(tb[(size_t)s5 * NHID + lane]);
            a6 += w6 * bf2f(tb[(size_t)s6 * NHID + lane]);
            a7 += w7 * bf2f(tb[(size_t)s7 * NHID + lane]);
        }
        for (; k + 3 < rem; k += 4) {
            int s0 = __shfl(ent[0], k);     float w0 = __int_as_float(__shfl(ent[1], k));
            int s1 = __shfl(ent[0], k + 1); float w1 = __int_as_float(__shfl(ent[1], k + 1));
            int s2 = __shfl(ent[0], k + 2); float w2 = __int_as_float(__shfl(ent[1], k + 2));
            int s3 = __shfl(ent[0], k + 3); float w3 = __int_as_float(__shfl(ent[1], k + 3));
            a0 += w0 * bf2f(tb[(size_t)s0 * NHID + lane]);
            a1 += w1 * bf2f(tb[(size_t)s1 * NHID + lane]);
            a2 += w2 * bf2f(tb[(size_t)s2 * NHID + lane]);
            a3 += w3 * bf2f(tb[(size_t)s3 * NHID + lane]);
        }
        for (; k < rem; ++k) {
            int s0 = __shfl(ent[0], k); float w0 = __int_as_float(__shfl(ent[1], k));
            a0 += w0 * bf2f(tb[(size_t)s0 * NHID + lane]);
        }
    }

    float sum = ((a0 + a1) + (a2 + a3)) + ((a4 + a5) + (a6 + a7));
    float di = dis[node];
    if (LAYER == 1) {
        float h = di * sum + bias[lane];
        h = (h > 0.0f) ? h : h * NEG_SLOPE;
        outp[(size_t)node * NHID + lane] = f2bfu(di * h);
    } else {
        outp[(size_t)node * NHID + lane] = f2bfu(di * sum);
    }
}

// ---------------- K7: tail — h3 = lrelu(u2@Wc2+bc2); out = log_softmax(h3@Wo+bo) ----------------

__global__ __launch_bounds__(256) void tail_kernel(const unsigned short* __restrict__ ub,
                                                   const float* __restrict__ Wc2,
                                                   const float* __restrict__ bc2,
                                                   const float* __restrict__ Wo,
                                                   const float* __restrict__ bo,
                                                   float* __restrict__ outp, int n) {
    __shared__ __align__(16) float WsA[NHID * 64];           // 16KB: Wc2 then Wo(2560)
    __shared__ __align__(16) unsigned short hs[64 * 68];     // 8.7KB bf16 h3
    __shared__ float bos[NCLS];

    int tid = threadIdx.x;
    for (int i = tid; i < NHID * 16; i += 256) ((float4*)WsA)[i] = ((const float4*)Wc2)[i];
    __syncthreads();

    int c4 = (tid & 15) * 4;
    int r0l = (tid >> 4) * 4;
    int base = blockIdx.x * 64;

    int rr[4];
#pragma unroll
    for (int i = 0; i < 4; ++i) rr[i] = min(base + r0l + i, n - 1);

    float acc[4][4] = {};
#pragma unroll 2
    for (int kk = 0; kk < NHID; kk += 4) {
        f32x4 av[4], bv[4];
#pragma unroll
        for (int i = 0; i < 4; ++i) {
            ushort4 uv = *(const ushort4*)&ub[(size_t)rr[i] * NHID + kk];
            av[i][0] = bf2f(uv.x); av[i][1] = bf2f(uv.y);
            av[i][2] = bf2f(uv.z); av[i][3] = bf2f(uv.w);
        }
#pragma unroll
        for (int q = 0; q < 4; ++q) bv[q] = *(const f32x4*)&WsA[(kk + q) * 64 + c4];
#pragma unroll
        for (int i = 0; i < 4; ++i) {
#pragma unroll
            for (int q = 0; q < 4; ++q) {
                float a = av[i][q];
#pragma unroll
                for (int j = 0; j < 4; ++j) acc[i][j] += a * bv[q][j];
            }
        }
    }

#pragma unroll
    for (int i = 0; i < 4; ++i) {
#pragma unroll
        for (int j = 0; j < 4; ++j) {
            float v = acc[i][j] + bc2[c4 + j];
            v = (v > 0.0f) ? v : v * NEG_SLOPE;
            hs[(r0l + i) * 68 + c4 + j] = f2bfu(v);
        }
    }
    __syncthreads();

    // reload WsA[0..2559] = Wo (64x40)
    for (int i = tid; i < NHID * NCLS / 4; i += 256) ((float4*)WsA)[i] = ((const float4*)Wo)[i];
    if (tid < NCLS) bos[tid] = bo[tid];
    __syncthreads();

    // phase 2: row = tid>>2 (0..63), cols c0..c0+9
    int row = tid >> 2;
    int c0 = (tid & 3) * 10;
    int node = base + row;

    float z[10];
#pragma unroll
    for (int j = 0; j < 10; ++j) z[j] = 0.0f;

#pragma unroll 2
    for (int k0 = 0; k0 < NHID; k0 += 4) {
        ushort4 hv = *(const ushort4*)&hs[row * 68 + k0];
        float h0 = bf2f(hv.x), h1 = bf2f(hv.y), h2 = bf2f(hv.z), h3 = bf2f(hv.w);
        const float* w0 = &WsA[(k0 + 0) * NCLS + c0];
        const float* w1 = &WsA[(k0 + 1) * NCLS + c0];
        const float* w2 = &WsA[(k0 + 2) * NCLS + c0];
        const float* w3 = &WsA[(k0 + 3) * NCLS + c0];
#pragma unroll
        for (int j = 0; j < 10; ++j)
            z[j] += h0 * w0[j] + h1 * w1[j] + h2 * w2[j] + h3 * w3[j];
    }
#pragma unroll
    for (int j = 0; j < 10; ++j) z[j] += bos[c0 + j];

    float m = z[0];
#pragma unroll
    for (int j = 1; j < 10; ++j) m = fmaxf(m, z[j]);
    m = fmaxf(m, __shfl_xor(m, 1));
    m = fmaxf(m, __shfl_xor(m, 2));

    float s = 0.0f;
#pragma unroll
    for (int j = 0; j < 10; ++j) s += expf(z[j] - m);
    s += __shfl_xor(s, 1);
    s += __shfl_xor(s, 2);
    float ls = logf(s);

    if (node < n) {
#pragma unroll
        for (int j = 0; j < 10; ++j)
            outp[(size_t)node * NCLS + c0 + j] = z[j] - m - ls;
    }
}

// ---------------- launch ----------------

extern "C" void kernel_launch(void* const* d_in, const int* in_sizes, int n_in,
                              void* d_out, int out_size, void* d_ws, size_t ws_size,
                              hipStream_t stream) {
    const float* x   = (const float*)d_in[0];
    const int*   ei  = (const int*)d_in[1];   // [2, E] flat
    const float* ew  = (const float*)d_in[2];
    const float* W1  = (const float*)d_in[3];
    const float* b1  = (const float*)d_in[4];
    const float* Wc1 = (const float*)d_in[5];
    const float* bc1 = (const float*)d_in[6];
    const float* Wc2 = (const float*)d_in[7];
    const float* bc2 = (const float*)d_in[8];
    const float* Wo  = (const float*)d_in[9];
    const float* bo  = (const float*)d_in[10];
    float* out = (float*)d_out;

    const int N = in_sizes[0] / NFEATS;
    const int E = in_sizes[1] / 2;
    const int* src = ei;
    const int* dst = ei + E;

    const int ngrp   = (N + GSPAN_S - 1) >> GSH_S;    // 196
    const int nStage = (E + SB - 1) / SB;             // 782
    const int nTileG1= (N + 127) / 128;               // 782 (128-row tiles)
    const int nTile  = (N + 63) / 64;                 // 1563
    const int aggBlocks = (N + 3) / 4;

    // workspace layout (~81 MB)
    float*          bufA  = (float*)d_ws;                          // N*64 f32 (h1)
    unsigned short* t1b   = (unsigned short*)(bufA + (size_t)N * NHID);  // N*64 bf16 (t1', later u2)
    unsigned short* h2b   = t1b + (size_t)N * NHID;                // N*64 bf16 (h2')
    int2*  staged  = (int2*)(h2b + (size_t)N * NHID);              // ngrp*GCAP_S
    int2*  staged2 = staged + (size_t)ngrp * GCAP_S;               // ngrp*GCAP_S
    float* dis     = (float*)(staged2 + (size_t)ngrp * GCAP_S);    // N
    int*   gcur    = (int*)(dis + N);                              // ngrp (pad to 8B)
    int2*  nodeptr = (int2*)(gcur + ((ngrp + 1) & ~1));            // N

    // K1: zero group cursors
    hipMemsetAsync(gcur, 0, ngrp * sizeof(int), stream);

    // K2: coarse staged binning + h1 = lrelu(x@W1+b1) -> bufA
    stage_gemm1_kernel<<<nStage + nTileG1, 512, 0, stream>>>(
        src, dst, ew, gcur, staged, E, nStage, ngrp, x, W1, b1, bufA, N, nTileG1);

    // K3: merged deg/dis + node-sort -> staged2, nodeptr
    degsort_kernel<<<ngrp, 1024, 0, stream>>>(gcur, staged, staged2, dis, nodeptr, N);

    // K4: t1' = dis ⊙ (h1@Wc1) -> t1b (bf16)
    gemm2s_kernel<<<nTile, 256, 0, stream>>>(bufA, Wc1, dis, t1b, N);

    // K5: h2' = dis ⊙ lrelu(dis*(agg) + bc1) -> h2b (bf16)
    agg_kernel<1><<<aggBlocks, 256, 0, stream>>>(nodeptr, staged2, t1b, dis, bc1, h2b, N);

    // K6: u2 = dis*(agg(h2')) -> t1b reused as u2 (bf16)
    agg_kernel<2><<<aggBlocks, 256, 0, stream>>>(nodeptr, staged2, h2b, dis, nullptr, t1b, N);

    // K7: tail
    tail_kernel<<<nTile, 256, 0, stream>>>(t1b, Wc2, bc2, Wo, bo, out, N);
}

// Round 14
// 264.835 us; speedup vs baseline: 1.0824x; 1.0824x over previous
//
#include <hip/hip_runtime.h>
#include <hip/hip_bf16.h>
#include <math.h>

#define NFEATS 128
#define NHID   64
#define NCLS   40
#define NEG_SLOPE 0.01f

#define GSH_S  9                // log2(stage group span)
#define GSPAN_S 512             // nodes per stage group
#define GCAP_S 9216             // staged capacity per group (mean 8192, +11 sigma)
#define SB     2048             // edges per stage block (8/thread at 256 threads)

typedef float f32x4 __attribute__((ext_vector_type(4)));
typedef int   i32x2 __attribute__((ext_vector_type(2)));

// bf16 helpers (raw ushort storage, RNE rounding)
__device__ inline unsigned short f2bfu(float v) {
    union { float f; unsigned int u; } x; x.f = v;
    unsigned int r = (x.u + 0x7FFFu + ((x.u >> 16) & 1u)) >> 16;
    return (unsigned short)r;
}
__device__ inline float bf2f(unsigned short u) {
    union { unsigned int u32; float f; } x; x.u32 = ((unsigned int)u) << 16;
    return x.f;
}

// ---- role split: interleave nA blocks with nB blocks (1:1 striping, then tail) ----
__device__ inline void role_split(int i, int nA, int nB, int* ia, int* ib) {
    *ia = -1; *ib = -1;
    int m2 = 2 * min(nA, nB);
    if (i < m2) { if (i & 1) *ib = i >> 1; else *ia = i >> 1; }
    else if (nA > nB) *ia = i - nB;
    else *ib = i - nA;
}

// ---------------- K2: staged binning (issue-early loads, split atomic/store) + GEMM1 ----------------
// stage role: 2048 edges/block, 8/thread. All global loads issued in pass A (latency hides
// under hist atomics + barriers). Pass B: 8 independent LDS atomics, then 8 stores.

__global__ __launch_bounds__(256) void stage_gemm1_kernel(
    const int* __restrict__ srcA, const int* __restrict__ dstA, const float* __restrict__ ew,
    int* __restrict__ gcur, int2* __restrict__ staged, int E, int nStage, int ngrp,
    const float* __restrict__ x, const float* __restrict__ W1, const float* __restrict__ b1,
    float* __restrict__ h1, int n, int nTile) {
    __shared__ __align__(16) float Ws[64 * 64];   // 16KB; stage role aliases as int[512]

    int ia, ib;
    role_split(blockIdx.x, nStage, nTile, &ia, &ib);
    int tid = threadIdx.x;

    if (ia >= 0) {
        int* hist = (int*)Ws;         // [256] (ngrp<=256)
        int* wcur = ((int*)Ws) + 256; // [256]
        if (tid < 256) hist[tid] = 0;
        __syncthreads();

        int q0 = (ia * SB) >> 2;                 // int4-quad base
        int qend = min(q0 + SB / 4, E >> 2);
        int dcache[8], scache[8];
        float wcache[8];

        // pass A: issue ALL loads early; histogram on dst (no-return LDS atomics)
#pragma unroll
        for (int it = 0; it < 2; ++it) {
            int q = q0 + it * 256 + tid;
            bool ok = (q < qend);
            int4 d4 = ok ? ((const int4*)dstA)[q] : make_int4(-1, -1, -1, -1);
            int4 s4 = ok ? ((const int4*)srcA)[q] : make_int4(0, 0, 0, 0);
            float4 w4 = ok ? ((const float4*)ew)[q] : make_float4(0, 0, 0, 0);
            dcache[it * 4 + 0] = d4.x; dcache[it * 4 + 1] = d4.y;
            dcache[it * 4 + 2] = d4.z; dcache[it * 4 + 3] = d4.w;
            scache[it * 4 + 0] = s4.x; scache[it * 4 + 1] = s4.y;
            scache[it * 4 + 2] = s4.z; scache[it * 4 + 3] = s4.w;
            wcache[it * 4 + 0] = w4.x; wcache[it * 4 + 1] = w4.y;
            wcache[it * 4 + 2] = w4.z; wcache[it * 4 + 3] = w4.w;
#pragma unroll
            for (int j = 0; j < 4; ++j)
                if (dcache[it * 4 + j] >= 0) atomicAdd(&hist[dcache[it * 4 + j] >> GSH_S], 1);
        }
        if (ia == nStage - 1) {
            for (int e = (E & ~3) + tid; e < E; e += 256) atomicAdd(&hist[dstA[e] >> GSH_S], 1);
        }
        __syncthreads();

        // reserve per-group regions
        if (tid < ngrp) {
            int c = hist[tid];
            wcur[tid] = (c > 0) ? atomicAdd(&gcur[tid], c) : 0;
        }
        __syncthreads();

        // pass B phase 1: 8 independent LDS cursor atomics
        int pos[8];
#pragma unroll
        for (int j = 0; j < 8; ++j) {
            int d = dcache[j];
            pos[j] = (d >= 0) ? atomicAdd(&wcur[d >> GSH_S], 1) : GCAP_S;
        }
        // pass B phase 2: stores
#pragma unroll
        for (int j = 0; j < 8; ++j) {
            int d = dcache[j];
            if (d >= 0 && pos[j] < GCAP_S)
                staged[(size_t)(d >> GSH_S) * GCAP_S + pos[j]] =
                    make_int2(((d & (GSPAN_S - 1)) << 17) | scache[j], __float_as_int(wcache[j]));
        }
        if (ia == nStage - 1) {
            for (int e = (E & ~3) + tid; e < E; e += 256) {
                int d = dstA[e];
                int g = d >> GSH_S;
                int p = atomicAdd(&wcur[g], 1);
                if (p < GCAP_S)
                    staged[(size_t)g * GCAP_S + p] =
                        make_int2(((d & (GSPAN_S - 1)) << 17) | srcA[e], __float_as_int(ew[e]));
            }
        }
        return;
    }

    // ---- gemm role: h1 = lrelu(x @ W1 + b1), 64x64 tile, 4x4 micro-tile ----
    int c4 = (tid & 15) * 4;
    int r0 = ib * 64 + (tid >> 4) * 4;
    int rr[4];
#pragma unroll
    for (int i = 0; i < 4; ++i) rr[i] = min(r0 + i, n - 1);

    float acc[4][4] = {};
    for (int ph = 0; ph < 2; ++ph) {
        __syncthreads();
        for (int i = tid; i < 64 * 16; i += 256)
            ((float4*)Ws)[i] = ((const float4*)W1)[ph * 1024 + i];
        __syncthreads();
#pragma unroll 2
        for (int kk = 0; kk < 64; kk += 4) {
            f32x4 av[4], bv[4];
#pragma unroll
            for (int i = 0; i < 4; ++i)
                av[i] = __builtin_nontemporal_load(
                    (const f32x4*)&x[(size_t)rr[i] * NFEATS + ph * 64 + kk]);
#pragma unroll
            for (int q = 0; q < 4; ++q) bv[q] = *(const f32x4*)&Ws[(kk + q) * 64 + c4];
#pragma unroll
            for (int i = 0; i < 4; ++i) {
#pragma unroll
                for (int q = 0; q < 4; ++q) {
                    float a = av[i][q];
#pragma unroll
                    for (int j = 0; j < 4; ++j) acc[i][j] += a * bv[q][j];
                }
            }
        }
    }

#pragma unroll
    for (int i = 0; i < 4; ++i) {
        int rw = r0 + i;
        if (rw >= n) break;
        float4 o;
        float* oa = (float*)&o;
#pragma unroll
        for (int j = 0; j < 4; ++j) {
            float v = acc[i][j] + b1[c4 + j];
            oa[j] = (v > 0.0f) ? v : v * NEG_SLOPE;
        }
        *(float4*)&h1[(size_t)rw * 64 + c4] = o;
    }
}

// ---------------- K3: merged deg/dis + node-sort (512 thr, one block per coarse group) ----------------

__global__ __launch_bounds__(512) void degsort_kernel(
    const int* __restrict__ gcur, const int2* __restrict__ staged,
    int2* __restrict__ staged2, float* __restrict__ dis,
    int2* __restrict__ nodeptr, int n) {
    __shared__ float deg[GSPAN_S];
    __shared__ int hist[GSPAN_S], base[GSPAN_S], cur[GSPAN_S];

    int tid = threadIdx.x;
    int g = blockIdx.x;
    deg[tid] = 0.0f;
    hist[tid] = 0;
    __syncthreads();

    int cnt = min(gcur[g], GCAP_S);
    const int2* sl = staged + (size_t)g * GCAP_S;
    for (int i = tid; i < cnt; i += 512) {
        int2 r = sl[i];
        int dl = r.x >> 17;
        atomicAdd(&deg[dl], __int_as_float(r.y));
        atomicAdd(&hist[dl], 1);
    }
    __syncthreads();

    int node = g * GSPAN_S + tid;
    if (node < n) dis[node] = rsqrtf(1.0f + deg[tid]);

    // exclusive scan of hist
    base[tid] = hist[tid];
    __syncthreads();
    for (int off = 1; off < GSPAN_S; off <<= 1) {
        int t_ = (tid >= off) ? base[tid - off] : 0;
        __syncthreads();
        base[tid] += t_;
        __syncthreads();
    }
    int ex = base[tid] - hist[tid];
    base[tid] = ex;
    cur[tid] = ex;
    __syncthreads();

    if (node < n) nodeptr[node] = make_int2(g * GCAP_S + ex, hist[tid]);

    int2* out = staged2 + (size_t)g * GCAP_S;
    for (int i = tid; i < cnt; i += 512) {
        int2 r = sl[i];
        int dl = r.x >> 17;
        int pos = atomicAdd(&cur[dl], 1);
        out[pos] = make_int2(r.x & 0x1FFFF, r.y);
    }
}

// ---------------- K4: GEMM2 standalone: t1' = dis ⊙ (h1 @ Wc1) -> bf16 ----------------

__global__ __launch_bounds__(256) void gemm2s_kernel(
    const float* __restrict__ in, const float* __restrict__ W, const float* __restrict__ dis,
    unsigned short* __restrict__ outp, int n) {
    __shared__ __align__(16) float Ws[NHID * 64];
    int tid = threadIdx.x;
    for (int i = tid; i < NHID * 16; i += 256) ((float4*)Ws)[i] = ((const float4*)W)[i];
    __syncthreads();

    int c4 = (tid & 15) * 4;
    int r0 = blockIdx.x * 64 + (tid >> 4) * 4;
    int rr[4];
#pragma unroll
    for (int i = 0; i < 4; ++i) rr[i] = min(r0 + i, n - 1);

    float acc[4][4] = {};
#pragma unroll 2
    for (int kk = 0; kk < NHID; kk += 4) {
        f32x4 av[4], bv[4];
#pragma unroll
        for (int i = 0; i < 4; ++i)
            av[i] = __builtin_nontemporal_load((const f32x4*)&in[(size_t)rr[i] * NHID + kk]);
#pragma unroll
        for (int q = 0; q < 4; ++q) bv[q] = *(const f32x4*)&Ws[(kk + q) * 64 + c4];
#pragma unroll
        for (int i = 0; i < 4; ++i) {
#pragma unroll
            for (int q = 0; q < 4; ++q) {
                float a = av[i][q];
#pragma unroll
                for (int j = 0; j < 4; ++j) acc[i][j] += a * bv[q][j];
            }
        }
    }

#pragma unroll
    for (int i = 0; i < 4; ++i) {
        int rw = r0 + i;
        if (rw >= n) break;
        float dr = dis[rw];
        ushort4 o;
        o.x = f2bfu(dr * acc[i][0]); o.y = f2bfu(dr * acc[i][1]);
        o.z = f2bfu(dr * acc[i][2]); o.w = f2bfu(dr * acc[i][3]);
        *(ushort4*)&outp[(size_t)rw * 64 + c4] = o;
    }
}

// ---------------- K5/K6: aggregation (wave per node, bf16 row gathers, 8 chains) ----------------

template <int LAYER>
__global__ __launch_bounds__(256) void agg_kernel(const int2* __restrict__ nodeptr,
                                                  const int2* __restrict__ recs0,
                                                  const unsigned short* __restrict__ tb,
                                                  const float* __restrict__ dis,
                                                  const float* __restrict__ bias,
                                                  unsigned short* __restrict__ outp, int n) {
    int wv = threadIdx.x >> 6;
    int lane = threadIdx.x & 63;
    int node = blockIdx.x * 4 + wv;
    if (node >= n) return;

    int2 np = nodeptr[node];
    int start = np.x, c = np.y;
    float a0 = bf2f(tb[(size_t)node * NHID + lane]);   // self term t'[d]
    float a1 = 0.0f, a2 = 0.0f, a3 = 0.0f;
    float a4 = 0.0f, a5 = 0.0f, a6 = 0.0f, a7 = 0.0f;

    const i32x2* recs = (const i32x2*)(recs0 + start);
    for (int b = 0; b < c; b += 64) {
        int rem = min(64, c - b);
        i32x2 ent = (lane < rem) ? __builtin_nontemporal_load(recs + b + lane) : (i32x2){0, 0};
        int k = 0;
        for (; k + 7 < rem; k += 8) {
            int s0 = __shfl(ent[0], k);     float w0 = __int_as_float(__shfl(ent[1], k));
            int s1 = __shfl(ent[0], k + 1); float w1 = __int_as_float(__shfl(ent[1], k + 1));
            int s2 = __shfl(ent[0], k + 2); float w2 = __int_as_float(__shfl(ent[1], k + 2));
            int s3 = __shfl(ent[0], k + 3); float w3 = __int_as_float(__shfl(ent[1], k + 3));
            int s4 = __shfl(ent[0], k + 4); float w4 = __int_as_float(__shfl(ent[1], k + 4));
            int s5 = __shfl(ent[0], k + 5); float w5 = __int_as_float(__shfl(ent[1], k + 5));
            int s6 = __shfl(ent[0], k + 6); float w6 = __int_as_float(__shfl(ent[1], k + 6));
            int s7 = __shfl(ent[0], k + 7); float w7 = __int_as_float(__shfl(ent[1], k + 7));
            a0 += w0 * bf2f(tb[(size_t)s0 * NHID + lane]);
            a1 += w1 * bf2f(tb[(size_t)s1 * NHID + lane]);
            a2 += w2 * bf2f(tb[(size_t)s2 * NHID + lane]);
            a3 += w3 * bf2f(tb[(size_t)s3 * NHID + lane]);
            a4 += w4 * bf2f(tb[(size_t)s4 * NHID + lane]);
            a5 += w5 * bf2f(tb[(size_t)s5 * NHID + lane]);
            a6 += w6 * bf2f(tb[(size_t)s6 * NHID + lane]);
            a7 += w7 * bf2f(tb[(size_t)s7 * NHID + lane]);
        }
        for (; k + 3 < rem; k += 4) {
            int s0 = __shfl(ent[0], k);     float w0 = __int_as_float(__shfl(ent[1], k));
            int s1 = __shfl(ent[0], k + 1); float w1 = __int_as_float(__shfl(ent[1], k + 1));
            int s2 = __shfl(ent[0], k + 2); float w2 = __int_as_float(__shfl(ent[1], k + 2));
            int s3 = __shfl(ent[0], k + 3); float w3 = __int_as_float(__shfl(ent[1], k + 3));
            a0 += w0 * bf2f(tb[(size_t)s0 * NHID + lane]);
            a1 += w1 * bf2f(tb[(size_t)s1 * NHID + lane]);
            a2 += w2 * bf2f(tb[(size_t)s2 * NHID + lane]);
            a3 += w3 * bf2f(tb[(size_t)s3 * NHID + lane]);
        }
        for (; k < rem; ++k) {
            int s0 = __shfl(ent[0], k); float w0 = __int_as_float(__shfl(ent[1], k));
            a0 += w0 * bf2f(tb[(size_t)s0 * NHID + lane]);
        }
    }

    float sum = ((a0 + a1) + (a2 + a3)) + ((a4 + a5) + (a6 + a7));
    float di = dis[node];
    if (LAYER == 1) {
        float h = di * sum + bias[lane];
        h = (h > 0.0f) ? h : h * NEG_SLOPE;
        outp[(size_t)node * NHID + lane] = f2bfu(di * h);
    } else {
        outp[(size_t)node * NHID + lane] = f2bfu(di * sum);
    }
}

// ---------------- K7: tail — h3 = lrelu(u2@Wc2+bc2); out = log_softmax(h3@Wo+bo) ----------------

__global__ __launch_bounds__(256) void tail_kernel(const unsigned short* __restrict__ ub,
                                                   const float* __restrict__ Wc2,
                                                   const float* __restrict__ bc2,
                                                   const float* __restrict__ Wo,
                                                   const float* __restrict__ bo,
                                                   float* __restrict__ outp, int n) {
    __shared__ __align__(16) float WsA[NHID * 64];           // 16KB: Wc2 then Wo(2560)
    __shared__ __align__(16) unsigned short hs[64 * 68];     // 8.7KB bf16 h3
    __shared__ float bos[NCLS];

    int tid = threadIdx.x;
    for (int i = tid; i < NHID * 16; i += 256) ((float4*)WsA)[i] = ((const float4*)Wc2)[i];
    __syncthreads();

    int c4 = (tid & 15) * 4;
    int r0l = (tid >> 4) * 4;
    int base = blockIdx.x * 64;

    int rr[4];
#pragma unroll
    for (int i = 0; i < 4; ++i) rr[i] = min(base + r0l + i, n - 1);

    float acc[4][4] = {};
#pragma unroll 2
    for (int kk = 0; kk < NHID; kk += 4) {
        f32x4 av[4], bv[4];
#pragma unroll
        for (int i = 0; i < 4; ++i) {
            ushort4 uv = *(const ushort4*)&ub[(size_t)rr[i] * NHID + kk];
            av[i][0] = bf2f(uv.x); av[i][1] = bf2f(uv.y);
            av[i][2] = bf2f(uv.z); av[i][3] = bf2f(uv.w);
        }
#pragma unroll
        for (int q = 0; q < 4; ++q) bv[q] = *(const f32x4*)&WsA[(kk + q) * 64 + c4];
#pragma unroll
        for (int i = 0; i < 4; ++i) {
#pragma unroll
            for (int q = 0; q < 4; ++q) {
                float a = av[i][q];
#pragma unroll
                for (int j = 0; j < 4; ++j) acc[i][j] += a * bv[q][j];
            }
        }
    }

#pragma unroll
    for (int i = 0; i < 4; ++i) {
#pragma unroll
        for (int j = 0; j < 4; ++j) {
            float v = acc[i][j] + bc2[c4 + j];
            v = (v > 0.0f) ? v : v * NEG_SLOPE;
            hs[(r0l + i) * 68 + c4 + j] = f2bfu(v);
        }
    }
    __syncthreads();

    // reload WsA[0..2559] = Wo (64x40)
    for (int i = tid; i < NHID * NCLS / 4; i += 256) ((float4*)WsA)[i] = ((const float4*)Wo)[i];
    if (tid < NCLS) bos[tid] = bo[tid];
    __syncthreads();

    // phase 2: row = tid>>2 (0..63), cols c0..c0+9
    int row = tid >> 2;
    int c0 = (tid & 3) * 10;
    int node = base + row;

    float z[10];
#pragma unroll
    for (int j = 0; j < 10; ++j) z[j] = 0.0f;

#pragma unroll 2
    for (int k0 = 0; k0 < NHID; k0 += 4) {
        ushort4 hv = *(const ushort4*)&hs[row * 68 + k0];
        float h0 = bf2f(hv.x), h1 = bf2f(hv.y), h2 = bf2f(hv.z), h3 = bf2f(hv.w);
        const float* w0 = &WsA[(k0 + 0) * NCLS + c0];
        const float* w1 = &WsA[(k0 + 1) * NCLS + c0];
        const float* w2 = &WsA[(k0 + 2) * NCLS + c0];
        const float* w3 = &WsA[(k0 + 3) * NCLS + c0];
#pragma unroll
        for (int j = 0; j < 10; ++j)
            z[j] += h0 * w0[j] + h1 * w1[j] + h2 * w2[j] + h3 * w3[j];
    }
#pragma unroll
    for (int j = 0; j < 10; ++j) z[j] += bos[c0 + j];

    float m = z[0];
#pragma unroll
    for (int j = 1; j < 10; ++j) m = fmaxf(m, z[j]);
    m = fmaxf(m, __shfl_xor(m, 1));
    m = fmaxf(m, __shfl_xor(m, 2));

    float s = 0.0f;
#pragma unroll
    for (int j = 0; j < 10; ++j) s += expf(z[j] - m);
    s += __shfl_xor(s, 1);
    s += __shfl_xor(s, 2);
    float ls = logf(s);

    if (node < n) {
#pragma unroll
        for (int j = 0; j < 10; ++j)
            outp[(size_t)node * NCLS + c0 + j] = z[j] - m - ls;
    }
}

// ---------------- launch ----------------

extern "C" void kernel_launch(void* const* d_in, const int* in_sizes, int n_in,
                              void* d_out, int out_size, void* d_ws, size_t ws_size,
                              hipStream_t stream) {
    const float* x   = (const float*)d_in[0];
    const int*   ei  = (const int*)d_in[1];   // [2, E] flat
    const float* ew  = (const float*)d_in[2];
    const float* W1  = (const float*)d_in[3];
    const float* b1  = (const float*)d_in[4];
    const float* Wc1 = (const float*)d_in[5];
    const float* bc1 = (const float*)d_in[6];
    const float* Wc2 = (const float*)d_in[7];
    const float* bc2 = (const float*)d_in[8];
    const float* Wo  = (const float*)d_in[9];
    const float* bo  = (const float*)d_in[10];
    float* out = (float*)d_out;

    const int N = in_sizes[0] / NFEATS;
    const int E = in_sizes[1] / 2;
    const int* src = ei;
    const int* dst = ei + E;

    const int ngrp   = (N + GSPAN_S - 1) >> GSH_S;    // 196
    const int nStage = (E + SB - 1) / SB;             // 782
    const int nTile  = (N + 63) / 64;                 // 1563
    const int aggBlocks = (N + 3) / 4;

    // workspace layout (~81 MB)
    float*          bufA  = (float*)d_ws;                          // N*64 f32 (h1)
    unsigned short* t1b   = (unsigned short*)(bufA + (size_t)N * NHID);  // N*64 bf16 (t1', later u2)
    unsigned short* h2b   = t1b + (size_t)N * NHID;                // N*64 bf16 (h2')
    int2*  staged  = (int2*)(h2b + (size_t)N * NHID);              // ngrp*GCAP_S
    int2*  staged2 = staged + (size_t)ngrp * GCAP_S;               // ngrp*GCAP_S
    float* dis     = (float*)(staged2 + (size_t)ngrp * GCAP_S);    // N
    int*   gcur    = (int*)(dis + N);                              // ngrp (pad to 8B)
    int2*  nodeptr = (int2*)(gcur + ((ngrp + 1) & ~1));            // N

    // K1: zero group cursors
    hipMemsetAsync(gcur, 0, ngrp * sizeof(int), stream);

    // K2: coarse staged binning + h1 = lrelu(x@W1+b1) -> bufA
    stage_gemm1_kernel<<<nStage + nTile, 256, 0, stream>>>(
        src, dst, ew, gcur, staged, E, nStage, ngrp, x, W1, b1, bufA, N, nTile);

    // K3: merged deg/dis + node-sort -> staged2, nodeptr
    degsort_kernel<<<ngrp, 512, 0, stream>>>(gcur, staged, staged2, dis, nodeptr, N);

    // K4: t1' = dis ⊙ (h1@Wc1) -> t1b (bf16)
    gemm2s_kernel<<<nTile, 256, 0, stream>>>(bufA, Wc1, dis, t1b, N);

    // K5: h2' = dis ⊙ lrelu(dis*(agg) + bc1) -> h2b (bf16)
    agg_kernel<1><<<aggBlocks, 256, 0, stream>>>(nodeptr, staged2, t1b, dis, bc1, h2b, N);

    // K6: u2 = dis*(agg(h2')) -> t1b reused as u2 (bf16)
    agg_kernel<2><<<aggBlocks, 256, 0, stream>>>(nodeptr, staged2, h2b, dis, nullptr, t1b, N);

    // K7: tail
    tail_kernel<<<nTile, 256, 0, stream>>>(t1b, Wc2, bc2, Wo, bo, out, N);
}